// Round 7
// baseline (810.136 us; speedup 1.0000x reference)
//
#include <hip/hip_runtime.h>
#include <stdint.h>

#define S_LEN 2048
#define D_DIM 128
#define BK 64
#define NIT (S_LEN / BK)
#define KIMG_BYTES (32u * 2048u * 256u)   // 16.78 MB bf16 K images (swizzled)

typedef __attribute__((ext_vector_type(8))) short bf16x8;
typedef __attribute__((ext_vector_type(4))) float f32x4;
typedef __attribute__((ext_vector_type(4))) int i32x4;
typedef __attribute__((ext_vector_type(4))) float fvec4;

__device__ __forceinline__ unsigned rnd16(float x) {
    union { float f; unsigned u; } c; c.f = x;
    return c.u + 0x8000u;
}
__device__ __forceinline__ unsigned pack2(float lo, float hi) {
    return __builtin_amdgcn_perm(rnd16(hi), rnd16(lo), 0x07060302);
}

__device__ __forceinline__ void async_cp16(const void* g, void* l) {
    __builtin_amdgcn_global_load_lds(
        (const __attribute__((address_space(1))) unsigned int*)g,
        (__attribute__((address_space(3))) unsigned int*)l, 16, 0, 0);
}

// ---- prep: K -> bf16 swizzled image; V -> V^T bf16 tiled+swizzled image ----
__global__ __launch_bounds__(256)
void prep(const float* __restrict__ k, const float* __restrict__ v,
          unsigned char* __restrict__ kimg, unsigned char* __restrict__ vimg) {
    if (blockIdx.x < 4096) {
        const unsigned g = blockIdx.x * 256 + threadIdx.x;
        const int cb = g & 15, t = (g >> 4) & 2047, head = g >> 15;
        const float* src = k + ((size_t)head * 2048 + t) * 128 + cb * 8;
        float4 f0 = *(const float4*)src, f1 = *(const float4*)(src + 4);
        uint4 u;
        u.x = pack2(f0.x, f0.y); u.y = pack2(f0.z, f0.w);
        u.z = pack2(f1.x, f1.y); u.w = pack2(f1.z, f1.w);
        *(uint4*)(kimg + ((size_t)(head * 2048 + t) * 16 + (cb ^ (t & 15))) * 16) = u;
    } else {
        const int b = blockIdx.x - 4096;  // (head, chunk)
        const int head = b >> 5, it = b & 31;
        const int tid = threadIdx.x;
        const int tg = (tid & 15) * 4, dg = (tid >> 4) * 8;
        const float* src = v + (size_t)head * 2048 * 128 + (size_t)(it * 64 + tg) * 128;
        float4 va[4], vb4[4];
#pragma unroll
        for (int r = 0; r < 4; ++r) {
            va[r]  = *(const float4*)(src + r * 128 + dg);
            vb4[r] = *(const float4*)(src + r * 128 + dg + 4);
        }
        unsigned char* dst = vimg + ((size_t)head * 32 + it) * 16384;
        const int half = (tg & 4) * 2;
#pragma unroll
        for (int i = 0; i < 4; ++i) {
            const int d = dg + i;
            uint2 wv;
            wv.x = pack2(((const float*)&va[0])[i], ((const float*)&va[1])[i]);
            wv.y = pack2(((const float*)&va[2])[i], ((const float*)&va[3])[i]);
            *(uint2*)(dst + d * 128 + (((tg >> 3) ^ (d & 7)) * 16) + half) = wv;
            const int d2 = dg + 4 + i;
            uint2 w2;
            w2.x = pack2(((const float*)&vb4[0])[i], ((const float*)&vb4[1])[i]);
            w2.y = pack2(((const float*)&vb4[2])[i], ((const float*)&vb4[3])[i]);
            *(uint2*)(dst + d2 * 128 + (((tg >> 3) ^ (d2 & 7)) * 16) + half) = w2;
        }
    }
}

// ---- main: 512 blocks x 256 thr. XCD-aware remap: bh = blockIdx&31 puts all
// 16 q-tile blocks of head h on XCD h%8 (round-robin dispatch) -> each XCD's
// L2 holds its 4 head-images (4 MB); image DMA becomes L2 hits. Mask loads
// and O stores are non-temporal so the 537 MB stream doesn't evict images.
__global__ __launch_bounds__(256, 2)
void fused_main(const float* __restrict__ q, const float* __restrict__ mask,
                const unsigned char* __restrict__ kimg,
                const unsigned char* __restrict__ vimg,
                float* __restrict__ out) {
    __shared__ __align__(16) unsigned short smem[2 * 16384];  // 2 x (K 16KB + Vt 16KB)

    const int tid  = threadIdx.x;
    const int lane = tid & 63;
    const int w    = tid >> 6;
    const int l15  = lane & 15;
    const int qd   = lane >> 4;

    const int bh = blockIdx.x & 31;          // head -> XCD bh%8
    const int s0 = (blockIdx.x >> 5) * 128;  // q-tile

    const float* qp = q + (size_t)bh * S_LEN * D_DIM;
    const float* mp = mask + (size_t)bh * S_LEN * S_LEN;
    float*       op = out + (size_t)bh * S_LEN * D_DIM;
    const unsigned char* kb = kimg + (size_t)bh * (2048u * 256u);
    const unsigned char* vb = vimg + (size_t)bh * (32u * 16384u);

    // ---- Q fragments straight from global fp32 ----
    bf16x8 qf[2][4];
#pragma unroll
    for (int sj = 0; sj < 2; ++sj)
#pragma unroll
        for (int kc = 0; kc < 4; ++kc) {
            const float* qq = qp + (size_t)(s0 + 32 * w + 16 * sj + l15) * D_DIM
                            + kc * 32 + qd * 8;
            float4 f0 = *(const float4*)qq, f1 = *(const float4*)(qq + 4);
            union { uint4 u; bf16x8 b; } cv;
            cv.u.x = pack2(f0.x, f0.y); cv.u.y = pack2(f0.z, f0.w);
            cv.u.z = pack2(f1.x, f1.y); cv.u.w = pack2(f1.z, f1.w);
            qf[sj][kc] = cv.b;
        }

    // ---- mask registers (non-temporal loads; double-buffered) ----
    const float* mbase = mp + (size_t)(s0 + 32 * w + l15) * S_LEN + 4 * qd;
    fvec4 mcur[4][2], mnxt[4][2];
#pragma unroll
    for (int ti = 0; ti < 4; ++ti)
#pragma unroll
        for (int sj = 0; sj < 2; ++sj)
            mcur[ti][sj] = __builtin_nontemporal_load(
                (const fvec4*)(mbase + (size_t)(16 * sj) * S_LEN + 16 * ti));

    // ---- DMA tile 0 into buf 0 ----
    {
        unsigned short* lb = smem;
#pragma unroll
        for (int s = 0; s < 8; ++s) {
            const int seg = w + s * 4;
            const unsigned char* g = (seg < 16) ? (kb + seg * 1024)
                                                : (vb + (seg - 16) * 1024);
            async_cp16(g + lane * 16, (void*)(lb + seg * 512 + lane * 8));
        }
    }
    __syncthreads();

    f32x4 acc_o[2][8];
#pragma unroll
    for (int i = 0; i < 2; ++i)
#pragma unroll
        for (int j = 0; j < 8; ++j) acc_o[i][j] = (f32x4){0.f, 0.f, 0.f, 0.f};

    const int a0 = ((2 * (qd & 1)) * 16 + l15) * 4;
    const int a1 = a0 + 64;
    const bool hi = (qd >= 2);

    int cur = 0;
    for (int it = 0; it < NIT; ++it) {
        const bool pf = (it + 1 < NIT);
        const int nxt = cur ^ 1;
        const unsigned short* Ks = smem + cur * 16384;
        const unsigned short* Vt = smem + cur * 16384 + 8192;

        // ---- issue DMA + nt mask prefetch for tile it+1 ----
        if (pf) {
            const unsigned char* kt = kb + (size_t)(it + 1) * 16384;
            const unsigned char* vt = vb + (size_t)(it + 1) * 16384;
            unsigned short* lb = smem + nxt * 16384;
#pragma unroll
            for (int s = 0; s < 8; ++s) {
                const int seg = w + s * 4;
                const unsigned char* g = (seg < 16) ? (kt + seg * 1024)
                                                    : (vt + (seg - 16) * 1024);
                async_cp16(g + lane * 16, (void*)(lb + seg * 512 + lane * 8));
            }
            const float* mb = mbase + (size_t)(it + 1) * BK;
#pragma unroll
            for (int ti = 0; ti < 4; ++ti)
#pragma unroll
                for (int sj = 0; sj < 2; ++sj)
                    mnxt[ti][sj] = __builtin_nontemporal_load(
                        (const fvec4*)(mb + (size_t)(16 * sj) * S_LEN + 16 * ti));
        }

        // ---- S^T = K·Q^T (swizzled, conflict-free b128) ----
        f32x4 acc_s[4][2];
#pragma unroll
        for (int i = 0; i < 4; ++i)
#pragma unroll
            for (int j = 0; j < 2; ++j) acc_s[i][j] = (f32x4){0.f, 0.f, 0.f, 0.f};
#pragma unroll
        for (int kc = 0; kc < 4; ++kc) {
            bf16x8 af[4];
#pragma unroll
            for (int ti = 0; ti < 4; ++ti)
                af[ti] = *(const bf16x8*)&Ks[((16 * ti + l15) << 7) +
                                             (((kc * 4 + qd) ^ l15) << 3)];
#pragma unroll
            for (int ti = 0; ti < 4; ++ti)
#pragma unroll
                for (int sj = 0; sj < 2; ++sj)
                    acc_s[ti][sj] = __builtin_amdgcn_mfma_f32_16x16x32_bf16(
                        af[ti], qf[sj][kc], acc_s[ti][sj], 0, 0, 0);
        }

        // ---- P = S^T ∘ mask -> packed bf16 ----
        int pu[4][2][2];
#pragma unroll
        for (int ti = 0; ti < 4; ++ti)
#pragma unroll
            for (int sj = 0; sj < 2; ++sj) {
                f32x4 sv = acc_s[ti][sj];
                fvec4 m = mcur[ti][sj];
                pu[ti][sj][0] = (int)pack2(sv[0] * m[0], sv[1] * m[1]);
                pu[ti][sj][1] = (int)pack2(sv[2] * m[2], sv[3] * m[3]);
            }

        // ---- quad-exchange + O += P·V ----
#pragma unroll
        for (int kc2 = 0; kc2 < 2; ++kc2) {
            bf16x8 ap[2];
#pragma unroll
            for (int sj = 0; sj < 2; ++sj) {
                const int tA = 2 * kc2, tB = 2 * kc2 + 1;
                int w0a = __builtin_amdgcn_ds_bpermute(a0, pu[tA][sj][0]);
                int w0b = __builtin_amdgcn_ds_bpermute(a0, pu[tB][sj][0]);
                int w1a = __builtin_amdgcn_ds_bpermute(a0, pu[tA][sj][1]);
                int w1b = __builtin_amdgcn_ds_bpermute(a0, pu[tB][sj][1]);
                int w2a = __builtin_amdgcn_ds_bpermute(a1, pu[tA][sj][0]);
                int w2b = __builtin_amdgcn_ds_bpermute(a1, pu[tB][sj][0]);
                int w3a = __builtin_amdgcn_ds_bpermute(a1, pu[tA][sj][1]);
                int w3b = __builtin_amdgcn_ds_bpermute(a1, pu[tB][sj][1]);
                union { i32x4 i; bf16x8 b; } u;
                u.i = (i32x4){hi ? w0b : w0a, hi ? w1b : w1a,
                              hi ? w2b : w2a, hi ? w3b : w3a};
                ap[sj] = u.b;
            }
#pragma unroll
            for (int dj = 0; dj < 8; ++dj) {
                bf16x8 bvv = *(const bf16x8*)&Vt[((16 * dj + l15) << 6) +
                                                 (((kc2 * 4 + qd) ^ (l15 & 7)) << 3)];
#pragma unroll
                for (int sj = 0; sj < 2; ++sj)
                    acc_o[sj][dj] = __builtin_amdgcn_mfma_f32_16x16x32_bf16(
                        ap[sj], bvv, acc_o[sj][dj], 0, 0, 0);
            }
        }

        __syncthreads();  // drains DMA + guards buffer swap
        if (pf) {
#pragma unroll
            for (int ti = 0; ti < 4; ++ti)
#pragma unroll
                for (int sj = 0; sj < 2; ++sj) mcur[ti][sj] = mnxt[ti][sj];
        }
        cur = nxt;
    }

    // ---- epilogue (non-temporal stores) ----
#pragma unroll
    for (int si = 0; si < 2; ++si)
#pragma unroll
        for (int dj = 0; dj < 8; ++dj)
#pragma unroll
            for (int r = 0; r < 4; ++r) {
                const int srow = s0 + 32 * w + 16 * si + 4 * qd + r;
                __builtin_nontemporal_store(
                    acc_o[si][dj][r], op + (size_t)srow * D_DIM + 16 * dj + l15);
            }
}

extern "C" void kernel_launch(void* const* d_in, const int* in_sizes, int n_in,
                              void* d_out, int out_size, void* d_ws, size_t ws_size,
                              hipStream_t stream) {
    const float* q = (const float*)d_in[0];
    const float* k = (const float*)d_in[1];
    const float* v = (const float*)d_in[2];
    const float* m = (const float*)d_in[3];
    unsigned char* kimg = (unsigned char*)d_ws;
    unsigned char* vimg = kimg + KIMG_BYTES;
    prep<<<dim3(5120), dim3(256), 0, stream>>>(k, v, kimg, vimg);
    fused_main<<<dim3(512), dim3(256), 0, stream>>>(q, m, kimg, vimg, (float*)d_out);
}